// Round 10
// baseline (268.384 us; speedup 1.0000x reference)
//
#include <hip/hip_runtime.h>
#include <hip/hip_bf16.h>
#include <stdint.h>

typedef __attribute__((ext_vector_type(8))) short short8;
typedef __attribute__((ext_vector_type(4))) float f32x4;

#define QSCALE 0.18033688011112042f   // (1/8) * log2(e): folds softmax /sqrt(64) AND exp->exp2

__device__ __forceinline__ unsigned short f2bf(float f) {
  unsigned int u = __builtin_bit_cast(unsigned int, f);
  u += 0x7FFFu + ((u >> 16) & 1u);   // RNE
  return (unsigned short)(u >> 16);
}

__device__ __forceinline__ unsigned short f2bf_fast(float f) {
  __hip_bfloat16 h = __float2bfloat16(f);     // compiler emits good cvt (m240)
  return __builtin_bit_cast(unsigned short, h);
}

__device__ __forceinline__ float exp2_fast(float x) {
  float r; asm("v_exp_f32 %0, %1" : "=v"(r) : "v"(x)); return r;   // 2^x
}

#define GLD_LDS16(gp, lp) \
  __builtin_amdgcn_global_load_lds((const __attribute__((address_space(1))) void*)(gp), \
                                   (__attribute__((address_space(3))) void*)(lp), 16, 0, 0)

// ---------------- fused fp32 -> bf16 convert for x / Wqkv (q-rows pre-scaled) / Wo ------
__global__ __launch_bounds__(256) void cvt_all_kernel(
    const float* __restrict__ x, const float* __restrict__ Wqkv, const float* __restrict__ Wo,
    unsigned short* __restrict__ xb, unsigned short* __restrict__ Wqkvb,
    unsigned short* __restrict__ Wob) {
  int i = blockIdx.x * 256 + threadIdx.x;          // indexes 8-float chunks
  const float* src; unsigned short* dst; int local; float scale = 1.0f;
  if (i < 1048576) { src = x; dst = xb; local = i; }
  else if (i < 1048576 + 393216) {
    local = i - 1048576; src = Wqkv; dst = Wqkvb;
    int row = (local * 8) >> 10;                   // K = 1024 per row
    if (((row >> 6) % 3) == 0) scale = QSCALE;     // q rows: fold 1/sqrt(64) * log2(e)
  } else { local = i - 1441792; src = Wo; dst = Wob; }
  const float4* s4 = (const float4*)src;
  float4 a = s4[local * 2], b = s4[local * 2 + 1];
  uint4 o;
  o.x = (unsigned)f2bf(a.x * scale) | ((unsigned)f2bf(a.y * scale) << 16);
  o.y = (unsigned)f2bf(a.z * scale) | ((unsigned)f2bf(a.w * scale) << 16);
  o.z = (unsigned)f2bf(b.x * scale) | ((unsigned)f2bf(b.y * scale) << 16);
  o.w = (unsigned)f2bf(b.z * scale) | ((unsigned)f2bf(b.w * scale) << 16);
  *(uint4*)(dst + (size_t)local * 8) = o;
}

// ---------------- 128x128-tile bf16 GEMM, C = A @ B^T (+bias), m97 structure ----------
// EPI 0: scatter q/k as [B][H][S][64], v TRANSPOSED as [B][H][64][S]   EPI 1: fp32 [M][N]
template<int EPI>
__global__ __launch_bounds__(256, 2) void gemm_bt(
    const unsigned short* __restrict__ A, const unsigned short* __restrict__ Bw,
    const float* __restrict__ bias, void* o0, void* o1, void* o2,
    int M, int N, int K, int nbc)
{
  __shared__ __align__(16) unsigned short Asm[128 * 64];
  __shared__ __align__(16) unsigned short Bsm[128 * 64];
  int bid = blockIdx.x;
  int bc = bid % nbc, br = bid / nbc;
  int tid = threadIdx.x;
  int lane = tid & 63, w = tid >> 6;
  int l16 = lane & 15, g = lane >> 4;
  int wr = w >> 1, wc = w & 1;
  f32x4 acc[4][4];
  #pragma unroll
  for (int i = 0; i < 4; i++)
    #pragma unroll
    for (int j = 0; j < 4; j++) acc[i][j] = (f32x4){0.f, 0.f, 0.f, 0.f};

  const int nkt = K >> 6;
  for (int kt = 0; kt < nkt; ++kt) {
    __syncthreads();
    #pragma unroll
    for (int r = 0; r < 4; ++r) {
      int idx = tid + 256 * r;            // lane-contiguous per wave (gload_lds linear dest)
      int row = idx >> 3, s = idx & 7;
      int gofs = ((s ^ (row & 7)) << 3) + (kt << 6);   // pre-swizzled global source
      GLD_LDS16(A + (size_t)(br * 128 + row) * K + gofs, &Asm[idx << 3]);
      GLD_LDS16(Bw + (size_t)(bc * 128 + row) * K + gofs, &Bsm[idx << 3]);
    }
    __syncthreads();
    #pragma unroll
    for (int kk = 0; kk < 2; ++kk) {
      short8 af[4], bf[4];
      #pragma unroll
      for (int i = 0; i < 4; i++) {
        int rowa = wr * 64 + i * 16 + l16;
        af[i] = *(const short8*)&Asm[(rowa << 6) + ((((kk << 2) + g) ^ (rowa & 7)) << 3)];
        int rowb = wc * 64 + i * 16 + l16;
        bf[i] = *(const short8*)&Bsm[(rowb << 6) + ((((kk << 2) + g) ^ (rowb & 7)) << 3)];
      }
      #pragma unroll
      for (int i = 0; i < 4; i++)
        #pragma unroll
        for (int j = 0; j < 4; j++)
          acc[i][j] = __builtin_amdgcn_mfma_f32_16x16x32_bf16(af[i], bf[j], acc[i][j], 0, 0, 0);
    }
  }
  // epilogue: D row = g*4+jj, col = l16 (m89-verified layout)
  #pragma unroll
  for (int i = 0; i < 4; i++) {
    #pragma unroll
    for (int j = 0; j < 4; j++) {
      int n = bc * 128 + wc * 64 + j * 16 + l16;
      int m0 = br * 128 + wr * 64 + i * 16 + g * 4;
      if (EPI == 0) {
        int t = (n >> 6) % 3;
        int hh = n / 192, e = n & 63;
        float bval = bias[n]; if (t == 0) bval *= QSCALE;
        int bb = m0 >> 12, s0 = m0 & 4095;          // S = 4096; m0 4-aligned, no b-straddle
        if (t == 2) {                               // v: transposed [bh][e][S], b64-packed
          unsigned short p0 = f2bf(acc[i][j][0] + bval);
          unsigned short p1 = f2bf(acc[i][j][1] + bval);
          unsigned short p2 = f2bf(acc[i][j][2] + bval);
          unsigned short p3 = f2bf(acc[i][j][3] + bval);
          uint2 pk;
          pk.x = (unsigned)p0 | ((unsigned)p1 << 16);
          pk.y = (unsigned)p2 | ((unsigned)p3 << 16);
          unsigned short* vt = (unsigned short*)o2;
          *(uint2*)&vt[(((size_t)(bb * 16 + hh) * 64 + e) << 12) + s0] = pk;
        } else {
          unsigned short* dst = (unsigned short*)(t == 0 ? o0 : o1);
          #pragma unroll
          for (int jj = 0; jj < 4; jj++)
            dst[((((size_t)(bb * 16 + hh) << 12) + s0 + jj) << 6) + e] = f2bf(acc[i][j][jj] + bval);
        }
      } else {
        float* o = (float*)o0;
        float bval = bias[n];
        #pragma unroll
        for (int jj = 0; jj < 4; jj++)
          o[(size_t)(m0 + jj) * N + n] = acc[i][j][jj] + bval;
      }
    }
  }
}

// ---------------- banded flash attention (QBLK=256, q-set-interleaved inner loop) ------
// r9 structure/layouts kept bit-identical; restructured per tile: K frags read ONCE ->
// QK(qs0)+QK(qs1) -> softmax both -> ONE lgkmcnt fence -> V frags read ONCE ->
// PV(qs0)+PV(qs1). Ps split per q-set (LDS 64KB; grid is 2 blocks/CU regardless).
__global__ __launch_bounds__(512, 4) void attn_kernel(
    const unsigned short* __restrict__ qb, const unsigned short* __restrict__ kb,
    const unsigned short* __restrict__ vtb, const int* __restrict__ pmask,
    unsigned short* __restrict__ ctxb)
{
  const int S = 4096, HD = 64, WIN = 256;
  const float NEG = -1e38f;
  __shared__ __align__(16) unsigned short Ks[2][64 * 64];      // 16 KB
  __shared__ __align__(16) unsigned short Vts[2][64 * 64];     // 16 KB
  __shared__ __align__(16) unsigned short Ps[8][2][16 * 64];   // 32 KB (per wave, per q-set)

  int bid0 = blockIdx.x;
  int bid = (bid0 & 7) * (gridDim.x >> 3) + (bid0 >> 3);   // XCD swizzle: heads share L2
  int qt = bid & 15;            // S/256 tiles
  int bh = bid >> 4;
  int b = bh >> 4, h = bh & 15;

  const unsigned short* Q  = qb + (size_t)bh * S * HD;
  const unsigned short* Kg = kb + (size_t)bh * S * HD;
  const unsigned short* Vt = vtb + (size_t)bh * HD * S;
  const int* pmrow = pmask + (size_t)b * S;

  int tid = threadIdx.x;
  int lane = tid & 63, w = tid >> 6;
  int l16 = lane & 15, g = lane >> 4;

  int q0 = qt * 256;
  int qw = q0 + w * 32;

  short8 qf[2][2];
  #pragma unroll
  for (int qs = 0; qs < 2; ++qs)
    #pragma unroll
    for (int hh = 0; hh < 2; ++hh)
      qf[qs][hh] = *(const short8*)&Q[(size_t)(qw + qs * 16 + l16) * HD + hh * 32 + g * 8];

  f32x4 ctx[2][4];
  #pragma unroll
  for (int qs = 0; qs < 2; ++qs)
    #pragma unroll
    for (int dt = 0; dt < 4; ++dt) ctx[qs][dt] = (f32x4){0.f, 0.f, 0.f, 0.f};
  float lrun[2][4] = {{0.f,0.f,0.f,0.f},{0.f,0.f,0.f,0.f}};

  int kt0 = (q0 - WIN) >> 6; if (kt0 < 0) kt0 = 0;
  int kt1 = (q0 + 255 + WIN) >> 6; if (kt1 > 63) kt1 = 63;
  int nt = kt1 - kt0 + 1;

  // 512 threads stage one 64x64 K-unit and one 64x64 Vt-unit (8 KB each, 1 gload ea.)
#define STAGE(BUF, KT) do {                                                       \
    int kb_ = (KT) * 64;                                                          \
    int row_ = tid >> 3, s_ = tid & 7;                                            \
    int c_ = (s_ ^ (row_ & 7)) << 3;                                              \
    GLD_LDS16(Kg + (size_t)(kb_ + row_) * HD + c_, &Ks[BUF][tid << 3]);           \
    GLD_LDS16(Vt + (size_t)row_ * S + kb_ + c_, &Vts[BUF][tid << 3]);             \
  } while (0)

  STAGE(0, kt0);
  asm volatile("s_waitcnt vmcnt(0)" ::: "memory");
  __syncthreads();

  int cur = 0;
  for (int it = 0; it < nt; ++it) {
    int kbase = (kt0 + it) * 64;
    if (it + 1 < nt) STAGE(cur ^ 1, kt0 + it + 1);

    // per-q-set need (wave-uniform)
    bool need0 = (kbase >= qw - 319) && (kbase <= qw + 271);
    bool need1 = (kbase >= qw - 303) && (kbase <= qw + 287);   // Q0 = qw+16

    if (need0 || need1) {
      // tile padding mask: one ballot; all-valid fast path (bench mask is all-ones)
      unsigned long long bm = __ballot(pmrow[kbase + lane] != 0);
      bool allv = (~bm == 0ULL);

      // ---- K fragments ONCE per tile (q-set-invariant) ----
      short8 kf[8];
      #pragma unroll
      for (int k4 = 0; k4 < 4; ++k4) {
        int krow = k4 * 16 + l16;
        kf[2 * k4]     = *(const short8*)&Ks[cur][(krow << 6) + ((g ^ (l16 & 7)) << 3)];
        kf[2 * k4 + 1] = *(const short8*)&Ks[cur][(krow << 6) + (((4 + g) ^ (l16 & 7)) << 3)];
      }

      // ---- QK^T both q-sets (independent MFMA chains) ----
      f32x4 sc[2][4];
      __builtin_amdgcn_s_setprio(1);
      #pragma unroll
      for (int qs = 0; qs < 2; ++qs) {
        if (qs == 0 ? !need0 : !need1) continue;
        #pragma unroll
        for (int k4 = 0; k4 < 4; ++k4) {
          f32x4 s = (f32x4){0.f, 0.f, 0.f, 0.f};
          s = __builtin_amdgcn_mfma_f32_16x16x32_bf16(qf[qs][0], kf[2 * k4], s, 0, 0, 0);
          sc[qs][k4] = __builtin_amdgcn_mfma_f32_16x16x32_bf16(qf[qs][1], kf[2 * k4 + 1], s, 0, 0, 0);
        }
      }
      __builtin_amdgcn_s_setprio(0);

      // ---- mask + exp2 + store P, both q-sets ----
      #pragma unroll
      for (int qs = 0; qs < 2; ++qs) {
        if (qs == 0 ? !need0 : !need1) continue;
        int Q0 = qw + qs * 16;
        bool full = (kbase >= Q0 - 241) && (kbase <= Q0 + 193); // whole tile in band
        int qbase = Q0 + g * 4;
        if (!full) {                      // band-edge tiles only: mask out-of-band
          #pragma unroll
          for (int k4 = 0; k4 < 4; ++k4) {
            int kg = kbase + k4 * 16 + l16;
            #pragma unroll
            for (int jj = 0; jj < 4; ++jj) {
              int dq = kg - (qbase + jj) + WIN;      // in [0,2*WIN] iff in band
              sc[qs][k4][jj] = ((unsigned)dq <= 2u * WIN) ? sc[qs][k4][jj] : NEG;
            }
          }
        }
        #pragma unroll
        for (int k4 = 0; k4 < 4; ++k4) {
          int col = k4 * 16 + l16;
          unsigned bit = (unsigned)(bm >> col) & 1u;   // key valid?
          #pragma unroll
          for (int jj = 0; jj < 4; ++jj) {
            float p = exp2_fast(sc[qs][k4][jj]);
            if (!allv) p = bit ? p : 0.f;
            lrun[qs][jj] += p;
            int row = g * 4 + jj;        // Ps XOR-swizzle: blk = (col>>3)^(row&7)
            Ps[w][qs][(row << 6) + ((((col >> 3) ^ (row & 7)) << 3) | (col & 7))] = f2bf_fast(p);
          }
        }
      }

      asm volatile("s_waitcnt lgkmcnt(0)" ::: "memory");  // P writes visible wave-wide
      __builtin_amdgcn_sched_barrier(0);

      // ---- V fragments ONCE per tile, then PV both q-sets ----
      short8 vf[8];
      #pragma unroll
      for (int dt = 0; dt < 4; ++dt) {
        int drow = dt * 16 + l16;
        vf[2 * dt]     = *(const short8*)&Vts[cur][(drow << 6) + ((g ^ (l16 & 7)) << 3)];
        vf[2 * dt + 1] = *(const short8*)&Vts[cur][(drow << 6) + (((4 + g) ^ (l16 & 7)) << 3)];
      }
      __builtin_amdgcn_s_setprio(1);
      #pragma unroll
      for (int qs = 0; qs < 2; ++qs) {
        if (qs == 0 ? !need0 : !need1) continue;
        short8 pf0 = *(const short8*)&Ps[w][qs][(l16 << 6) + ((g ^ (l16 & 7)) << 3)];
        short8 pf1 = *(const short8*)&Ps[w][qs][(l16 << 6) + (((4 + g) ^ (l16 & 7)) << 3)];
        #pragma unroll
        for (int dt = 0; dt < 4; ++dt) {
          ctx[qs][dt] = __builtin_amdgcn_mfma_f32_16x16x32_bf16(pf0, vf[2 * dt], ctx[qs][dt], 0, 0, 0);
          ctx[qs][dt] = __builtin_amdgcn_mfma_f32_16x16x32_bf16(pf1, vf[2 * dt + 1], ctx[qs][dt], 0, 0, 0);
        }
      }
      __builtin_amdgcn_s_setprio(0);
    }

    if (it + 1 < nt) {
      asm volatile("s_waitcnt vmcnt(0)" ::: "memory");  // next tile landed (issued pre-compute)
      __syncthreads();                                   // all waves done with cur
      cur ^= 1;
    }
  }
#undef STAGE

  // denominator reduce (once) + write ctx as bf16 in [B][S][H*64]
  #pragma unroll
  for (int qs = 0; qs < 2; ++qs) {
    #pragma unroll
    for (int jj = 0; jj < 4; ++jj) {
      float ps = lrun[qs][jj];
      #pragma unroll
      for (int mk = 1; mk < 16; mk <<= 1) ps += __shfl_xor(ps, mk);
      float rc = (ps > 0.f) ? (1.f / ps) : 0.f;
      int qrow = qw + qs * 16 + g * 4 + jj;
      size_t base = ((size_t)b * S + qrow) * 1024 + h * 64;
      #pragma unroll
      for (int dt = 0; dt < 4; ++dt)
        ctxb[base + dt * 16 + l16] = f2bf(ctx[qs][dt][jj] * rc);
    }
  }
}

// ---------------- launch ----------------------------------------------------------------
extern "C" void kernel_launch(void* const* d_in, const int* in_sizes, int n_in,
                              void* d_out, int out_size, void* d_ws, size_t ws_size,
                              hipStream_t stream) {
  const float* x     = (const float*)d_in[0];
  const int*   pmask = (const int*)d_in[1];
  const float* Wqkv  = (const float*)d_in[2];
  const float* bqkv  = (const float*)d_in[3];
  const float* Wo    = (const float*)d_in[4];
  const float* bo    = (const float*)d_in[5];

  // Memory map (56MB of ws + d_out doubling as q/k scratch):
  //   ws:    xb@0 (16MB) | Wqkvb@16MB (6MB) | Wob@22MB (2MB) | vtb@24MB (16MB) | ctxb@40MB (16MB)
  //   d_out: qbuf@0 (16MB) | kbuf@16MB (16MB)  -- dead before final GEMM overwrites d_out
  char* wsp = (char*)d_ws;
  unsigned short* xb    = (unsigned short*)(wsp);
  unsigned short* Wqkvb = (unsigned short*)(wsp + (size_t)(16u << 20));
  unsigned short* Wob   = (unsigned short*)(wsp + (size_t)(22u << 20));
  unsigned short* vtb   = (unsigned short*)(wsp + (size_t)(24u << 20));
  unsigned short* ctxb  = (unsigned short*)(wsp + (size_t)(40u << 20));
  unsigned short* qbuf  = (unsigned short*)d_out;
  unsigned short* kbuf  = (unsigned short*)d_out + (size_t)8388608;  // +16MB

  cvt_all_kernel<<<6144, 256, 0, stream>>>(x, Wqkv, Wo, xb, Wqkvb, Wob);

  gemm_bt<0><<<(8192 / 128) * (3072 / 128), 256, 0, stream>>>(
      xb, Wqkvb, bqkv, qbuf, kbuf, vtb, 8192, 3072, 1024, 3072 / 128);

  attn_kernel<<<512, 512, 0, stream>>>(qbuf, kbuf, vtb, pmask, ctxb);

  gemm_bt<1><<<(8192 / 128) * (1024 / 128), 256, 0, stream>>>(
      ctxb, Wob, bo, d_out, nullptr, nullptr, 8192, 1024, 1024, 1024 / 128);
}

// Round 11
// 149.063 us; speedup vs baseline: 1.8005x; 1.8005x over previous
//
#include <hip/hip_runtime.h>
#include <hip/hip_bf16.h>
#include <stdint.h>

typedef __attribute__((ext_vector_type(8))) short short8;
typedef __attribute__((ext_vector_type(4))) float f32x4;

#define QSCALE 0.18033688011112042f   // (1/8) * log2(e): folds softmax /sqrt(64) AND exp->exp2

__device__ __forceinline__ unsigned short f2bf(float f) {
  unsigned int u = __builtin_bit_cast(unsigned int, f);
  u += 0x7FFFu + ((u >> 16) & 1u);   // RNE
  return (unsigned short)(u >> 16);
}

__device__ __forceinline__ unsigned short f2bf_fast(float f) {
  __hip_bfloat16 h = __float2bfloat16(f);     // compiler emits good cvt (m240)
  return __builtin_bit_cast(unsigned short, h);
}

__device__ __forceinline__ float exp2_fast(float x) {
  float r; asm("v_exp_f32 %0, %1" : "=v"(r) : "v"(x)); return r;   // 2^x
}

#define GLD_LDS16(gp, lp) \
  __builtin_amdgcn_global_load_lds((const __attribute__((address_space(1))) void*)(gp), \
                                   (__attribute__((address_space(3))) void*)(lp), 16, 0, 0)

// ---------------- fused fp32 -> bf16 convert for x / Wqkv (q-rows pre-scaled) / Wo ------
__global__ __launch_bounds__(256) void cvt_all_kernel(
    const float* __restrict__ x, const float* __restrict__ Wqkv, const float* __restrict__ Wo,
    unsigned short* __restrict__ xb, unsigned short* __restrict__ Wqkvb,
    unsigned short* __restrict__ Wob) {
  int i = blockIdx.x * 256 + threadIdx.x;          // indexes 8-float chunks
  const float* src; unsigned short* dst; int local; float scale = 1.0f;
  if (i < 1048576) { src = x; dst = xb; local = i; }
  else if (i < 1048576 + 393216) {
    local = i - 1048576; src = Wqkv; dst = Wqkvb;
    int row = (local * 8) >> 10;                   // K = 1024 per row
    if (((row >> 6) % 3) == 0) scale = QSCALE;     // q rows: fold 1/sqrt(64) * log2(e)
  } else { local = i - 1441792; src = Wo; dst = Wob; }
  const float4* s4 = (const float4*)src;
  float4 a = s4[local * 2], b = s4[local * 2 + 1];
  uint4 o;
  o.x = (unsigned)f2bf(a.x * scale) | ((unsigned)f2bf(a.y * scale) << 16);
  o.y = (unsigned)f2bf(a.z * scale) | ((unsigned)f2bf(a.w * scale) << 16);
  o.z = (unsigned)f2bf(b.x * scale) | ((unsigned)f2bf(b.y * scale) << 16);
  o.w = (unsigned)f2bf(b.z * scale) | ((unsigned)f2bf(b.w * scale) << 16);
  *(uint4*)(dst + (size_t)local * 8) = o;
}

// ---------------- 128x128-tile bf16 GEMM, C = A @ B^T (+bias), m97 structure ----------
// EPI 0: scatter q/k as [B][H][S][64], v TRANSPOSED as [B][H][64][S]   EPI 1: fp32 [M][N]
// launch_bounds (256,4): VGPR use is 60 so the 128 cap changes nothing in regalloc, but
// guarantees 4 blocks/CU (was 2) -> more resident waves to hide the vmcnt(0)+barrier
// drain via m114-style cross-wave overlap.
template<int EPI>
__global__ __launch_bounds__(256, 4) void gemm_bt(
    const unsigned short* __restrict__ A, const unsigned short* __restrict__ Bw,
    const float* __restrict__ bias, void* o0, void* o1, void* o2,
    int M, int N, int K, int nbc)
{
  __shared__ __align__(16) unsigned short Asm[128 * 64];
  __shared__ __align__(16) unsigned short Bsm[128 * 64];
  int bid = blockIdx.x;
  int bc = bid % nbc, br = bid / nbc;
  int tid = threadIdx.x;
  int lane = tid & 63, w = tid >> 6;
  int l16 = lane & 15, g = lane >> 4;
  int wr = w >> 1, wc = w & 1;
  f32x4 acc[4][4];
  #pragma unroll
  for (int i = 0; i < 4; i++)
    #pragma unroll
    for (int j = 0; j < 4; j++) acc[i][j] = (f32x4){0.f, 0.f, 0.f, 0.f};

  const int nkt = K >> 6;
  for (int kt = 0; kt < nkt; ++kt) {
    __syncthreads();
    #pragma unroll
    for (int r = 0; r < 4; ++r) {
      int idx = tid + 256 * r;            // lane-contiguous per wave (gload_lds linear dest)
      int row = idx >> 3, s = idx & 7;
      int gofs = ((s ^ (row & 7)) << 3) + (kt << 6);   // pre-swizzled global source
      GLD_LDS16(A + (size_t)(br * 128 + row) * K + gofs, &Asm[idx << 3]);
      GLD_LDS16(Bw + (size_t)(bc * 128 + row) * K + gofs, &Bsm[idx << 3]);
    }
    __syncthreads();
    #pragma unroll
    for (int kk = 0; kk < 2; ++kk) {
      short8 af[4], bf[4];
      #pragma unroll
      for (int i = 0; i < 4; i++) {
        int rowa = wr * 64 + i * 16 + l16;
        af[i] = *(const short8*)&Asm[(rowa << 6) + ((((kk << 2) + g) ^ (rowa & 7)) << 3)];
        int rowb = wc * 64 + i * 16 + l16;
        bf[i] = *(const short8*)&Bsm[(rowb << 6) + ((((kk << 2) + g) ^ (rowb & 7)) << 3)];
      }
      #pragma unroll
      for (int i = 0; i < 4; i++)
        #pragma unroll
        for (int j = 0; j < 4; j++)
          acc[i][j] = __builtin_amdgcn_mfma_f32_16x16x32_bf16(af[i], bf[j], acc[i][j], 0, 0, 0);
    }
  }
  // epilogue: D row = g*4+jj, col = l16 (m89-verified layout)
  #pragma unroll
  for (int i = 0; i < 4; i++) {
    #pragma unroll
    for (int j = 0; j < 4; j++) {
      int n = bc * 128 + wc * 64 + j * 16 + l16;
      int m0 = br * 128 + wr * 64 + i * 16 + g * 4;
      if (EPI == 0) {
        int t = (n >> 6) % 3;
        int hh = n / 192, e = n & 63;
        float bval = bias[n]; if (t == 0) bval *= QSCALE;
        int bb = m0 >> 12, s0 = m0 & 4095;          // S = 4096; m0 4-aligned, no b-straddle
        if (t == 2) {                               // v: transposed [bh][e][S], b64-packed
          unsigned short p0 = f2bf(acc[i][j][0] + bval);
          unsigned short p1 = f2bf(acc[i][j][1] + bval);
          unsigned short p2 = f2bf(acc[i][j][2] + bval);
          unsigned short p3 = f2bf(acc[i][j][3] + bval);
          uint2 pk;
          pk.x = (unsigned)p0 | ((unsigned)p1 << 16);
          pk.y = (unsigned)p2 | ((unsigned)p3 << 16);
          unsigned short* vt = (unsigned short*)o2;
          *(uint2*)&vt[(((size_t)(bb * 16 + hh) * 64 + e) << 12) + s0] = pk;
        } else {
          unsigned short* dst = (unsigned short*)(t == 0 ? o0 : o1);
          #pragma unroll
          for (int jj = 0; jj < 4; jj++)
            dst[((((size_t)(bb * 16 + hh) << 12) + s0 + jj) << 6) + e] = f2bf(acc[i][j][jj] + bval);
        }
      } else {
        float* o = (float*)o0;
        float bval = bias[n];
        #pragma unroll
        for (int jj = 0; jj < 4; jj++)
          o[(size_t)(m0 + jj) * N + n] = acc[i][j][jj] + bval;
      }
    }
  }
}

// ---------------- banded flash attention (QBLK=256, per-qs tile skip, exp2 softmax) ----
// r9-exact (proven 149.1us total, conflicts=0, no spill). r10's fragment hoisting
// (kf[8]+vf[8]+sc[2][4] live together) exceeded the 128-VGPR budget and spilled
// (WRITE_SIZE 310MB) -- reverted. Register rule: one fragment array live at a time.
__global__ __launch_bounds__(512, 4) void attn_kernel(
    const unsigned short* __restrict__ qb, const unsigned short* __restrict__ kb,
    const unsigned short* __restrict__ vtb, const int* __restrict__ pmask,
    unsigned short* __restrict__ ctxb)
{
  const int S = 4096, HD = 64, WIN = 256;
  const float NEG = -1e38f;
  __shared__ __align__(16) unsigned short Ks[2][64 * 64];    // 16 KB
  __shared__ __align__(16) unsigned short Vts[2][64 * 64];   // 16 KB
  __shared__ __align__(16) unsigned short Ps[8][16 * 64];    // 16 KB (per wave, reused by q-sets)

  int bid0 = blockIdx.x;
  int bid = (bid0 & 7) * (gridDim.x >> 3) + (bid0 >> 3);   // XCD swizzle: heads share L2
  int qt = bid & 15;            // S/256 tiles
  int bh = bid >> 4;
  int b = bh >> 4, h = bh & 15;

  const unsigned short* Q  = qb + (size_t)bh * S * HD;
  const unsigned short* Kg = kb + (size_t)bh * S * HD;
  const unsigned short* Vt = vtb + (size_t)bh * HD * S;
  const int* pmrow = pmask + (size_t)b * S;

  int tid = threadIdx.x;
  int lane = tid & 63, w = tid >> 6;
  int l16 = lane & 15, g = lane >> 4;

  int q0 = qt * 256;
  int qw = q0 + w * 32;

  short8 qf[2][2];
  #pragma unroll
  for (int qs = 0; qs < 2; ++qs)
    #pragma unroll
    for (int hh = 0; hh < 2; ++hh)
      qf[qs][hh] = *(const short8*)&Q[(size_t)(qw + qs * 16 + l16) * HD + hh * 32 + g * 8];

  f32x4 ctx[2][4];
  #pragma unroll
  for (int qs = 0; qs < 2; ++qs)
    #pragma unroll
    for (int dt = 0; dt < 4; ++dt) ctx[qs][dt] = (f32x4){0.f, 0.f, 0.f, 0.f};
  float lrun[2][4] = {{0.f,0.f,0.f,0.f},{0.f,0.f,0.f,0.f}};

  int kt0 = (q0 - WIN) >> 6; if (kt0 < 0) kt0 = 0;
  int kt1 = (q0 + 255 + WIN) >> 6; if (kt1 > 63) kt1 = 63;
  int nt = kt1 - kt0 + 1;

  // 512 threads stage one 64x64 K-unit and one 64x64 Vt-unit (8 KB each, 1 gload ea.)
#define STAGE(BUF, KT) do {                                                       \
    int kb_ = (KT) * 64;                                                          \
    int row_ = tid >> 3, s_ = tid & 7;                                            \
    int c_ = (s_ ^ (row_ & 7)) << 3;                                              \
    GLD_LDS16(Kg + (size_t)(kb_ + row_) * HD + c_, &Ks[BUF][tid << 3]);           \
    GLD_LDS16(Vt + (size_t)row_ * S + kb_ + c_, &Vts[BUF][tid << 3]);             \
  } while (0)

  STAGE(0, kt0);
  asm volatile("s_waitcnt vmcnt(0)" ::: "memory");
  __syncthreads();

  int cur = 0;
  for (int it = 0; it < nt; ++it) {
    int kbase = (kt0 + it) * 64;
    if (it + 1 < nt) STAGE(cur ^ 1, kt0 + it + 1);

    // does any q-set of this wave need this tile? (wave-uniform)
    bool any0 = (kbase >= qw - 319) && (kbase <= qw + 271);
    bool any1 = (kbase >= qw - 303) && (kbase <= qw + 287);   // Q0 = qw+16

    if (any0 || any1) {
      // tile padding mask: one ballot; all-valid fast path (bench mask is all-ones)
      unsigned long long bm = __ballot(pmrow[kbase + lane] != 0);
      bool allv = (~bm == 0ULL);

      #pragma unroll
      for (int qs = 0; qs < 2; ++qs) {
        int Q0 = qw + qs * 16;
        if (kbase < Q0 - 319 || kbase > Q0 + 271) continue;   // wave-uniform skip
        bool full = (kbase >= Q0 - 241) && (kbase <= Q0 + 193); // whole tile in band

        // QK^T : S[q = g*4+jj][key = 16*k4 + l16]  (q pre-scaled by log2e/8)
        f32x4 sc[4];
        __builtin_amdgcn_s_setprio(1);
        #pragma unroll
        for (int k4 = 0; k4 < 4; ++k4) {
          int krow = k4 * 16 + l16;
          f32x4 s = (f32x4){0.f, 0.f, 0.f, 0.f};
          short8 kf0 = *(const short8*)&Ks[cur][(krow << 6) + ((g ^ (l16 & 7)) << 3)];
          s = __builtin_amdgcn_mfma_f32_16x16x32_bf16(qf[qs][0], kf0, s, 0, 0, 0);
          short8 kf1 = *(const short8*)&Ks[cur][(krow << 6) + (((4 + g) ^ (l16 & 7)) << 3)];
          s = __builtin_amdgcn_mfma_f32_16x16x32_bf16(qf[qs][1], kf1, s, 0, 0, 0);
          sc[k4] = s;
        }
        __builtin_amdgcn_s_setprio(0);

        int qbase = Q0 + g * 4;
        if (!full) {                      // band-edge tiles only: mask out-of-band
          #pragma unroll
          for (int k4 = 0; k4 < 4; ++k4) {
            int kg = kbase + k4 * 16 + l16;
            #pragma unroll
            for (int jj = 0; jj < 4; ++jj) {
              int dq = kg - (qbase + jj) + WIN;      // in [0,2*WIN] iff in band
              sc[k4][jj] = ((unsigned)dq <= 2u * WIN) ? sc[k4][jj] : NEG;
            }
          }
        }
        // exp2 + store P (scores already in log2 domain); padding via ballot bit
        #pragma unroll
        for (int k4 = 0; k4 < 4; ++k4) {
          int col = k4 * 16 + l16;
          unsigned bit = (unsigned)(bm >> col) & 1u;   // key valid?
          #pragma unroll
          for (int jj = 0; jj < 4; ++jj) {
            float p = exp2_fast(sc[k4][jj]);
            if (!allv) p = bit ? p : 0.f;
            lrun[qs][jj] += p;
            int row = g * 4 + jj;        // Ps XOR-swizzle: blk = (col>>3)^(row&7)
            Ps[w][(row << 6) + ((((col >> 3) ^ (row & 7)) << 3) | (col & 7))] = f2bf_fast(p);
          }
        }

        asm volatile("s_waitcnt lgkmcnt(0)" ::: "memory");  // P writes visible wave-wide
        __builtin_amdgcn_sched_barrier(0);
        // PV : ctx[q][d] += P[16q x 64keys] @ Vt[64d x 64keys]
        short8 pf0 = *(const short8*)&Ps[w][(l16 << 6) + ((g ^ (l16 & 7)) << 3)];
        short8 pf1 = *(const short8*)&Ps[w][(l16 << 6) + (((4 + g) ^ (l16 & 7)) << 3)];
        __builtin_amdgcn_s_setprio(1);
        #pragma unroll
        for (int dt = 0; dt < 4; ++dt) {
          int drow = dt * 16 + l16;
          short8 vf0 = *(const short8*)&Vts[cur][(drow << 6) + ((g ^ (drow & 7)) << 3)];
          ctx[qs][dt] = __builtin_amdgcn_mfma_f32_16x16x32_bf16(pf0, vf0, ctx[qs][dt], 0, 0, 0);
          short8 vf1 = *(const short8*)&Vts[cur][(drow << 6) + (((4 + g) ^ (drow & 7)) << 3)];
          ctx[qs][dt] = __builtin_amdgcn_mfma_f32_16x16x32_bf16(pf1, vf1, ctx[qs][dt], 0, 0, 0);
        }
        __builtin_amdgcn_s_setprio(0);
      }
    }

    if (it + 1 < nt) {
      asm volatile("s_waitcnt vmcnt(0)" ::: "memory");  // next tile landed (issued pre-compute)
      __syncthreads();                                   // all waves done with cur
      cur ^= 1;
    }
  }
#undef STAGE

  // denominator reduce (once) + write ctx as bf16 in [B][S][H*64]
  #pragma unroll
  for (int qs = 0; qs < 2; ++qs) {
    #pragma unroll
    for (int jj = 0; jj < 4; ++jj) {
      float ps = lrun[qs][jj];
      #pragma unroll
      for (int mk = 1; mk < 16; mk <<= 1) ps += __shfl_xor(ps, mk);
      float rc = (ps > 0.f) ? (1.f / ps) : 0.f;
      int qrow = qw + qs * 16 + g * 4 + jj;
      size_t base = ((size_t)b * S + qrow) * 1024 + h * 64;
      #pragma unroll
      for (int dt = 0; dt < 4; ++dt)
        ctxb[base + dt * 16 + l16] = f2bf(ctx[qs][dt][jj] * rc);
    }
  }
}

// ---------------- launch ----------------------------------------------------------------
extern "C" void kernel_launch(void* const* d_in, const int* in_sizes, int n_in,
                              void* d_out, int out_size, void* d_ws, size_t ws_size,
                              hipStream_t stream) {
  const float* x     = (const float*)d_in[0];
  const int*   pmask = (const int*)d_in[1];
  const float* Wqkv  = (const float*)d_in[2];
  const float* bqkv  = (const float*)d_in[3];
  const float* Wo    = (const float*)d_in[4];
  const float* bo    = (const float*)d_in[5];

  // Memory map (56MB of ws + d_out doubling as q/k scratch):
  //   ws:    xb@0 (16MB) | Wqkvb@16MB (6MB) | Wob@22MB (2MB) | vtb@24MB (16MB) | ctxb@40MB (16MB)
  //   d_out: qbuf@0 (16MB) | kbuf@16MB (16MB)  -- dead before final GEMM overwrites d_out
  char* wsp = (char*)d_ws;
  unsigned short* xb    = (unsigned short*)(wsp);
  unsigned short* Wqkvb = (unsigned short*)(wsp + (size_t)(16u << 20));
  unsigned short* Wob   = (unsigned short*)(wsp + (size_t)(22u << 20));
  unsigned short* vtb   = (unsigned short*)(wsp + (size_t)(24u << 20));
  unsigned short* ctxb  = (unsigned short*)(wsp + (size_t)(40u << 20));
  unsigned short* qbuf  = (unsigned short*)d_out;
  unsigned short* kbuf  = (unsigned short*)d_out + (size_t)8388608;  // +16MB

  cvt_all_kernel<<<6144, 256, 0, stream>>>(x, Wqkv, Wo, xb, Wqkvb, Wob);

  gemm_bt<0><<<(8192 / 128) * (3072 / 128), 256, 0, stream>>>(
      xb, Wqkvb, bqkv, qbuf, kbuf, vtb, 8192, 3072, 1024, 3072 / 128);

  attn_kernel<<<512, 512, 0, stream>>>(qbuf, kbuf, vtb, pmask, ctxb);

  gemm_bt<1><<<(8192 / 128) * (1024 / 128), 256, 0, stream>>>(
      ctxb, Wob, bo, d_out, nullptr, nullptr, 8192, 1024, 1024, 1024 / 128);
}

// Round 12
// 141.699 us; speedup vs baseline: 1.8940x; 1.0520x over previous
//
#include <hip/hip_runtime.h>
#include <hip/hip_bf16.h>
#include <stdint.h>

typedef __attribute__((ext_vector_type(8))) short short8;
typedef __attribute__((ext_vector_type(4))) float f32x4;

#define QSCALE 0.18033688011112042f   // (1/8) * log2(e): folds softmax /sqrt(64) AND exp->exp2

__device__ __forceinline__ unsigned short f2bf(float f) {
  unsigned int u = __builtin_bit_cast(unsigned int, f);
  u += 0x7FFFu + ((u >> 16) & 1u);   // RNE
  return (unsigned short)(u >> 16);
}

__device__ __forceinline__ unsigned short f2bf_fast(float f) {
  __hip_bfloat16 h = __float2bfloat16(f);     // compiler emits good cvt (m240)
  return __builtin_bit_cast(unsigned short, h);
}

__device__ __forceinline__ float exp2_fast(float x) {
  float r; asm("v_exp_f32 %0, %1" : "=v"(r) : "v"(x)); return r;   // 2^x
}

#define GLD_LDS16(gp, lp) \
  __builtin_amdgcn_global_load_lds((const __attribute__((address_space(1))) void*)(gp), \
                                   (__attribute__((address_space(3))) void*)(lp), 16, 0, 0)

// ---------------- fused fp32 -> bf16 convert for x / Wqkv (q-rows pre-scaled) / Wo ------
__global__ __launch_bounds__(256) void cvt_all_kernel(
    const float* __restrict__ x, const float* __restrict__ Wqkv, const float* __restrict__ Wo,
    unsigned short* __restrict__ xb, unsigned short* __restrict__ Wqkvb,
    unsigned short* __restrict__ Wob) {
  int i = blockIdx.x * 256 + threadIdx.x;          // indexes 8-float chunks
  const float* src; unsigned short* dst; int local; float scale = 1.0f;
  if (i < 1048576) { src = x; dst = xb; local = i; }
  else if (i < 1048576 + 393216) {
    local = i - 1048576; src = Wqkv; dst = Wqkvb;
    int row = (local * 8) >> 10;                   // K = 1024 per row
    if (((row >> 6) % 3) == 0) scale = QSCALE;     // q rows: fold 1/sqrt(64) * log2(e)
  } else { local = i - 1441792; src = Wo; dst = Wob; }
  const float4* s4 = (const float4*)src;
  float4 a = s4[local * 2], b = s4[local * 2 + 1];
  uint4 o;
  o.x = (unsigned)f2bf(a.x * scale) | ((unsigned)f2bf(a.y * scale) << 16);
  o.y = (unsigned)f2bf(a.z * scale) | ((unsigned)f2bf(a.w * scale) << 16);
  o.z = (unsigned)f2bf(b.x * scale) | ((unsigned)f2bf(b.y * scale) << 16);
  o.w = (unsigned)f2bf(b.z * scale) | ((unsigned)f2bf(b.w * scale) << 16);
  *(uint4*)(dst + (size_t)local * 8) = o;
}

// ---------------- 128x128-tile bf16 GEMM, C = A @ B^T (+bias), m97 structure ----------
// EPI 0: scatter q/k as [B][H][S][64], v TRANSPOSED as [B][H][64][S]   EPI 1: fp32 [M][N]
template<int EPI>
__global__ __launch_bounds__(256, 4) void gemm_bt(
    const unsigned short* __restrict__ A, const unsigned short* __restrict__ Bw,
    const float* __restrict__ bias, void* o0, void* o1, void* o2,
    int M, int N, int K, int nbc)
{
  __shared__ __align__(16) unsigned short Asm[128 * 64];
  __shared__ __align__(16) unsigned short Bsm[128 * 64];
  int bid = blockIdx.x;
  int bc = bid % nbc, br = bid / nbc;
  int tid = threadIdx.x;
  int lane = tid & 63, w = tid >> 6;
  int l16 = lane & 15, g = lane >> 4;
  int wr = w >> 1, wc = w & 1;
  f32x4 acc[4][4];
  #pragma unroll
  for (int i = 0; i < 4; i++)
    #pragma unroll
    for (int j = 0; j < 4; j++) acc[i][j] = (f32x4){0.f, 0.f, 0.f, 0.f};

  const int nkt = K >> 6;
  for (int kt = 0; kt < nkt; ++kt) {
    __syncthreads();
    #pragma unroll
    for (int r = 0; r < 4; ++r) {
      int idx = tid + 256 * r;            // lane-contiguous per wave (gload_lds linear dest)
      int row = idx >> 3, s = idx & 7;
      int gofs = ((s ^ (row & 7)) << 3) + (kt << 6);   // pre-swizzled global source
      GLD_LDS16(A + (size_t)(br * 128 + row) * K + gofs, &Asm[idx << 3]);
      GLD_LDS16(Bw + (size_t)(bc * 128 + row) * K + gofs, &Bsm[idx << 3]);
    }
    __syncthreads();
    #pragma unroll
    for (int kk = 0; kk < 2; ++kk) {
      short8 af[4], bf[4];
      #pragma unroll
      for (int i = 0; i < 4; i++) {
        int rowa = wr * 64 + i * 16 + l16;
        af[i] = *(const short8*)&Asm[(rowa << 6) + ((((kk << 2) + g) ^ (rowa & 7)) << 3)];
        int rowb = wc * 64 + i * 16 + l16;
        bf[i] = *(const short8*)&Bsm[(rowb << 6) + ((((kk << 2) + g) ^ (rowb & 7)) << 3)];
      }
      #pragma unroll
      for (int i = 0; i < 4; i++)
        #pragma unroll
        for (int j = 0; j < 4; j++)
          acc[i][j] = __builtin_amdgcn_mfma_f32_16x16x32_bf16(af[i], bf[j], acc[i][j], 0, 0, 0);
    }
  }
  // epilogue: D row = g*4+jj, col = l16 (m89-verified layout)
  #pragma unroll
  for (int i = 0; i < 4; i++) {
    #pragma unroll
    for (int j = 0; j < 4; j++) {
      int n = bc * 128 + wc * 64 + j * 16 + l16;
      int m0 = br * 128 + wr * 64 + i * 16 + g * 4;
      if (EPI == 0) {
        int t = (n >> 6) % 3;
        int hh = n / 192, e = n & 63;
        float bval = bias[n]; if (t == 0) bval *= QSCALE;
        int bb = m0 >> 12, s0 = m0 & 4095;          // S = 4096; m0 4-aligned, no b-straddle
        if (t == 2) {                               // v: transposed [bh][e][S], b64-packed
          unsigned short p0 = f2bf(acc[i][j][0] + bval);
          unsigned short p1 = f2bf(acc[i][j][1] + bval);
          unsigned short p2 = f2bf(acc[i][j][2] + bval);
          unsigned short p3 = f2bf(acc[i][j][3] + bval);
          uint2 pk;
          pk.x = (unsigned)p0 | ((unsigned)p1 << 16);
          pk.y = (unsigned)p2 | ((unsigned)p3 << 16);
          unsigned short* vt = (unsigned short*)o2;
          *(uint2*)&vt[(((size_t)(bb * 16 + hh) * 64 + e) << 12) + s0] = pk;
        } else {
          unsigned short* dst = (unsigned short*)(t == 0 ? o0 : o1);
          #pragma unroll
          for (int jj = 0; jj < 4; jj++)
            dst[((((size_t)(bb * 16 + hh) << 12) + s0 + jj) << 6) + e] = f2bf(acc[i][j][jj] + bval);
        }
      } else {
        float* o = (float*)o0;
        float bval = bias[n];
        #pragma unroll
        for (int jj = 0; jj < 4; jj++)
          o[(size_t)(m0 + jj) * N + n] = acc[i][j][jj] + bval;
      }
    }
  }
}

// ---------------- banded flash attention (QBLK=128, ONE q-set per wave) ----------------
// grid: (S/128) * B*H = 1024 blocks; 8 waves/block, wave owns 16 query rows.
// Same per-tile math/layouts/sync as r11 (proven: conflicts=0, no spill), with the q-set
// loop removed: grid 1024 -> up to 3 blocks/CU (LDS 48KB) -> 24 waves/CU if VGPR<=64.
// Register pressure strictly lower than r11 (ctx[4] not ctx[2][4]).
__global__ __launch_bounds__(512, 4) void attn_kernel(
    const unsigned short* __restrict__ qb, const unsigned short* __restrict__ kb,
    const unsigned short* __restrict__ vtb, const int* __restrict__ pmask,
    unsigned short* __restrict__ ctxb)
{
  const int S = 4096, HD = 64, WIN = 256;
  const float NEG = -1e38f;
  __shared__ __align__(16) unsigned short Ks[2][64 * 64];    // 16 KB
  __shared__ __align__(16) unsigned short Vts[2][64 * 64];   // 16 KB
  __shared__ __align__(16) unsigned short Ps[8][16 * 64];    // 16 KB (per wave)

  int bid0 = blockIdx.x;
  int bid = (bid0 & 7) * (gridDim.x >> 3) + (bid0 >> 3);   // XCD swizzle: 4 heads per XCD L2
  int qt = bid & 31;            // S/128 tiles
  int bh = bid >> 5;
  int b = bh >> 4, h = bh & 15;

  const unsigned short* Q  = qb + (size_t)bh * S * HD;
  const unsigned short* Kg = kb + (size_t)bh * S * HD;
  const unsigned short* Vt = vtb + (size_t)bh * HD * S;
  const int* pmrow = pmask + (size_t)b * S;

  int tid = threadIdx.x;
  int lane = tid & 63, w = tid >> 6;
  int l16 = lane & 15, g = lane >> 4;

  int q0 = qt * 128;
  int Q0 = q0 + w * 16;         // this wave's 16 query rows

  short8 qf[2];
  #pragma unroll
  for (int hh = 0; hh < 2; ++hh)
    qf[hh] = *(const short8*)&Q[(size_t)(Q0 + l16) * HD + hh * 32 + g * 8];

  f32x4 ctx[4];
  #pragma unroll
  for (int dt = 0; dt < 4; ++dt) ctx[dt] = (f32x4){0.f, 0.f, 0.f, 0.f};
  float lrun[4] = {0.f, 0.f, 0.f, 0.f};

  int kt0 = (q0 - WIN) >> 6; if (kt0 < 0) kt0 = 0;
  int kt1 = (q0 + 127 + WIN) >> 6; if (kt1 > 63) kt1 = 63;
  int nt = kt1 - kt0 + 1;

  // 512 threads stage one 64x64 K-unit and one 64x64 Vt-unit (8 KB each, 1 gload ea.)
#define STAGE(BUF, KT) do {                                                       \
    int kb_ = (KT) * 64;                                                          \
    int row_ = tid >> 3, s_ = tid & 7;                                            \
    int c_ = (s_ ^ (row_ & 7)) << 3;                                              \
    GLD_LDS16(Kg + (size_t)(kb_ + row_) * HD + c_, &Ks[BUF][tid << 3]);           \
    GLD_LDS16(Vt + (size_t)row_ * S + kb_ + c_, &Vts[BUF][tid << 3]);             \
  } while (0)

  STAGE(0, kt0);
  asm volatile("s_waitcnt vmcnt(0)" ::: "memory");
  __syncthreads();

  int cur = 0;
  for (int it = 0; it < nt; ++it) {
    int kbase = (kt0 + it) * 64;
    if (it + 1 < nt) STAGE(cur ^ 1, kt0 + it + 1);

    // wave-uniform: does this wave's 16-row band touch this tile?
    bool need = (kbase >= Q0 - 319) && (kbase <= Q0 + 271);

    if (need) {
      // tile padding mask: one ballot; all-valid fast path (bench mask is all-ones)
      unsigned long long bm = __ballot(pmrow[kbase + lane] != 0);
      bool allv = (~bm == 0ULL);
      bool full = (kbase >= Q0 - 241) && (kbase <= Q0 + 193);   // whole tile in band

      // QK^T : S[q = g*4+jj][key = 16*k4 + l16]  (q pre-scaled by log2e/8)
      f32x4 sc[4];
      __builtin_amdgcn_s_setprio(1);
      #pragma unroll
      for (int k4 = 0; k4 < 4; ++k4) {
        int krow = k4 * 16 + l16;
        f32x4 s = (f32x4){0.f, 0.f, 0.f, 0.f};
        short8 kf0 = *(const short8*)&Ks[cur][(krow << 6) + ((g ^ (l16 & 7)) << 3)];
        s = __builtin_amdgcn_mfma_f32_16x16x32_bf16(qf[0], kf0, s, 0, 0, 0);
        short8 kf1 = *(const short8*)&Ks[cur][(krow << 6) + (((4 + g) ^ (l16 & 7)) << 3)];
        s = __builtin_amdgcn_mfma_f32_16x16x32_bf16(qf[1], kf1, s, 0, 0, 0);
        sc[k4] = s;
      }
      __builtin_amdgcn_s_setprio(0);

      int qbase = Q0 + g * 4;
      if (!full) {                      // band-edge tiles only: mask out-of-band
        #pragma unroll
        for (int k4 = 0; k4 < 4; ++k4) {
          int kg = kbase + k4 * 16 + l16;
          #pragma unroll
          for (int jj = 0; jj < 4; ++jj) {
            int dq = kg - (qbase + jj) + WIN;      // in [0,2*WIN] iff in band
            sc[k4][jj] = ((unsigned)dq <= 2u * WIN) ? sc[k4][jj] : NEG;
          }
        }
      }
      // exp2 + store P (scores already in log2 domain); padding via ballot bit
      #pragma unroll
      for (int k4 = 0; k4 < 4; ++k4) {
        int col = k4 * 16 + l16;
        unsigned bit = (unsigned)(bm >> col) & 1u;   // key valid?
        #pragma unroll
        for (int jj = 0; jj < 4; ++jj) {
          float p = exp2_fast(sc[k4][jj]);
          if (!allv) p = bit ? p : 0.f;
          lrun[jj] += p;
          int row = g * 4 + jj;        // Ps XOR-swizzle: blk = (col>>3)^(row&7)
          Ps[w][(row << 6) + ((((col >> 3) ^ (row & 7)) << 3) | (col & 7))] = f2bf_fast(p);
        }
      }

      asm volatile("s_waitcnt lgkmcnt(0)" ::: "memory");  // P writes visible wave-wide
      __builtin_amdgcn_sched_barrier(0);
      // PV : ctx[q][d] += P[16q x 64keys] @ Vt[64d x 64keys]
      short8 pf0 = *(const short8*)&Ps[w][(l16 << 6) + ((g ^ (l16 & 7)) << 3)];
      short8 pf1 = *(const short8*)&Ps[w][(l16 << 6) + (((4 + g) ^ (l16 & 7)) << 3)];
      __builtin_amdgcn_s_setprio(1);
      #pragma unroll
      for (int dt = 0; dt < 4; ++dt) {
        int drow = dt * 16 + l16;
        short8 vf0 = *(const short8*)&Vts[cur][(drow << 6) + ((g ^ (drow & 7)) << 3)];
        ctx[dt] = __builtin_amdgcn_mfma_f32_16x16x32_bf16(pf0, vf0, ctx[dt], 0, 0, 0);
        short8 vf1 = *(const short8*)&Vts[cur][(drow << 6) + (((4 + g) ^ (drow & 7)) << 3)];
        ctx[dt] = __builtin_amdgcn_mfma_f32_16x16x32_bf16(pf1, vf1, ctx[dt], 0, 0, 0);
      }
      __builtin_amdgcn_s_setprio(0);
    }

    if (it + 1 < nt) {
      asm volatile("s_waitcnt vmcnt(0)" ::: "memory");  // next tile landed (issued pre-compute)
      __syncthreads();                                   // all waves done with cur
      cur ^= 1;
    }
  }
#undef STAGE

  // denominator reduce (once) + write ctx as bf16 in [B][S][H*64]
  #pragma unroll
  for (int jj = 0; jj < 4; ++jj) {
    float ps = lrun[jj];
    #pragma unroll
    for (int mk = 1; mk < 16; mk <<= 1) ps += __shfl_xor(ps, mk);
    float rc = (ps > 0.f) ? (1.f / ps) : 0.f;
    int qrow = Q0 + g * 4 + jj;
    size_t base = ((size_t)b * S + qrow) * 1024 + h * 64;
    #pragma unroll
    for (int dt = 0; dt < 4; ++dt)
      ctxb[base + dt * 16 + l16] = f2bf(ctx[dt][jj] * rc);
  }
}

// ---------------- launch ----------------------------------------------------------------
extern "C" void kernel_launch(void* const* d_in, const int* in_sizes, int n_in,
                              void* d_out, int out_size, void* d_ws, size_t ws_size,
                              hipStream_t stream) {
  const float* x     = (const float*)d_in[0];
  const int*   pmask = (const int*)d_in[1];
  const float* Wqkv  = (const float*)d_in[2];
  const float* bqkv  = (const float*)d_in[3];
  const float* Wo    = (const float*)d_in[4];
  const float* bo    = (const float*)d_in[5];

  // Memory map (56MB of ws + d_out doubling as q/k scratch):
  //   ws:    xb@0 (16MB) | Wqkvb@16MB (6MB) | Wob@22MB (2MB) | vtb@24MB (16MB) | ctxb@40MB (16MB)
  //   d_out: qbuf@0 (16MB) | kbuf@16MB (16MB)  -- dead before final GEMM overwrites d_out
  char* wsp = (char*)d_ws;
  unsigned short* xb    = (unsigned short*)(wsp);
  unsigned short* Wqkvb = (unsigned short*)(wsp + (size_t)(16u << 20));
  unsigned short* Wob   = (unsigned short*)(wsp + (size_t)(22u << 20));
  unsigned short* vtb   = (unsigned short*)(wsp + (size_t)(24u << 20));
  unsigned short* ctxb  = (unsigned short*)(wsp + (size_t)(40u << 20));
  unsigned short* qbuf  = (unsigned short*)d_out;
  unsigned short* kbuf  = (unsigned short*)d_out + (size_t)8388608;  // +16MB

  cvt_all_kernel<<<6144, 256, 0, stream>>>(x, Wqkv, Wo, xb, Wqkvb, Wob);

  gemm_bt<0><<<(8192 / 128) * (3072 / 128), 256, 0, stream>>>(
      xb, Wqkvb, bqkv, qbuf, kbuf, vtb, 8192, 3072, 1024, 3072 / 128);

  attn_kernel<<<1024, 512, 0, stream>>>(qbuf, kbuf, vtb, pmask, ctxb);

  gemm_bt<1><<<(8192 / 128) * (1024 / 128), 256, 0, stream>>>(
      ctxb, Wob, bo, d_out, nullptr, nullptr, 8192, 1024, 1024, 1024 / 128);
}